// Round 3
// baseline (306.597 us; speedup 1.0000x reference)
//
#include <hip/hip_runtime.h>

// LovaszSoftmaxLoss B=8, C=21, H=W=512 — sort-free counting-sort formulation.
// loss = sum_i e_i*(g_i - g_{i-1}) over descending-sorted errors; equal-key runs
// contribute e*(g(b)-g(a-1)) independent of tie order, so a histogram over
// 11-bit quantized keys (5 exp + 7 mantissa bits, ~0.4% rel) suffices vs the
// 2% threshold.
//
// R2 post-mortem: k_hist_scan (~230us) was LDS-u64-atomic bound at 168 blocks
// (66% CU util, 1 block/CU). R3: 32 partial histograms per row (5376 blocks,
// u32 packed (count<<18|labelsum) atomics, 4-way wave-private replicas, 32KB
// LDS -> 5 blocks/CU), non-atomic partial writeout, separate scan kernel.

#define NB     8
#define NC     21
#define NPIX   262144
#define NROWS  (NB * NC)     // 168
#define NBINS  2048          // key = exp5<<7 | mant7 ; valid keys {0} U [128,1920]
#define NPARTS 32
#define PPP    (NPIX / NPARTS)   // 8192 pixels per partial

// ---------------- Kernel A: softmax -> error -> packed u16 (key11|label5) ----------------
__global__ __launch_bounds__(256) void k_err(
    const float* __restrict__ x,
    const int* __restrict__ tgt,
    unsigned short* __restrict__ pk) {
  int t4 = blockIdx.x * blockDim.x + threadIdx.x;   // 0 .. NB*NPIX/4-1
  int b  = t4 >> 16;                                // 65536 quads per batch
  int n4 = (t4 & 65535) << 2;

  const float* xp = x + (size_t)b * NC * NPIX + n4;

  float v[NC][4];
  float m[4] = {-3.4e38f, -3.4e38f, -3.4e38f, -3.4e38f};
  #pragma unroll
  for (int c = 0; c < NC; ++c) {
    float4 t = *(const float4*)(xp + (size_t)c * NPIX);
    v[c][0] = t.x; v[c][1] = t.y; v[c][2] = t.z; v[c][3] = t.w;
    m[0] = fmaxf(m[0], t.x); m[1] = fmaxf(m[1], t.y);
    m[2] = fmaxf(m[2], t.z); m[3] = fmaxf(m[3], t.w);
  }
  float Z[4] = {0.f, 0.f, 0.f, 0.f};
  #pragma unroll
  for (int c = 0; c < NC; ++c) {
    #pragma unroll
    for (int j = 0; j < 4; ++j) {
      v[c][j] = __expf(v[c][j] - m[j]);
      Z[j] += v[c][j];
    }
  }
  float iZ[4];
  #pragma unroll
  for (int j = 0; j < 4; ++j) iZ[j] = 1.0f / Z[j];

  int4 tv = *(const int4*)(tgt + (size_t)b * NPIX + n4);
  int tl[4] = {tv.x, tv.y, tv.z, tv.w};

  unsigned short* op = pk + (size_t)b * NC * NPIX + n4;
  #pragma unroll
  for (int c = 0; c < NC; ++c) {
    ushort4 st;
    unsigned short* sp = (unsigned short*)&st;
    #pragma unroll
    for (int j = 0; j < 4; ++j) {
      float p = v[c][j] * iZ[j];
      float e = fabsf(((c == tl[j]) ? 1.0f : 0.0f) - p);   // e in [0,1]
      unsigned fb   = __float_as_uint(e);
      int      fexp = (int)(fb >> 23) - 127;               // e<=1 -> fexp<=0
      unsigned key  = (fexp < -14) ? 0u
                    : (((unsigned)(fexp + 15) << 7) | ((fb >> 16) & 127u));
      if (key > 1920u) key = 1920u;                        // safety (NaN guard)
      sp[j] = (unsigned short)((key << 5) | (unsigned)tl[j]);
    }
    *(ushort4*)(op + (size_t)c * NPIX) = st;
  }
}

// ---------------- Kernel B: partial LDS histograms (u32 packed) ----------------
// block = row*32 + part; 8192 pixels; count<=8192 (14b field), labelsum<=163840 (18b).
__global__ __launch_bounds__(256) void k_hist(
    const unsigned short* __restrict__ pk,
    unsigned* __restrict__ partial) {
  int blk  = blockIdx.x;
  int row  = blk >> 5;
  int part = blk & 31;
  int tid  = threadIdx.x;
  int wave = tid >> 6;                       // 4 waves -> 4 replicas

  __shared__ unsigned hist[4][NBINS];        // 32 KB
  #pragma unroll
  for (int i = tid; i < 4 * NBINS; i += 256) ((unsigned*)hist)[i] = 0;
  __syncthreads();

  unsigned* hr = hist[wave];
  const uint4* rp = (const uint4*)(pk + (size_t)row * NPIX + (size_t)part * PPP);
  #pragma unroll
  for (int it = 0; it < 4; ++it) {           // 1024 uint4 = 8192 u16 events
    uint4 q = rp[it * 256 + tid];
    unsigned w[4] = {q.x, q.y, q.z, q.w};
    #pragma unroll
    for (int k = 0; k < 4; ++k) {
      unsigned p0 = w[k] & 0xffffu, p1 = w[k] >> 16;
      atomicAdd(hr + (p0 >> 5), (1u << 18) | (p0 & 31u));
      atomicAdd(hr + (p1 >> 5), (1u << 18) | (p1 & 31u));
    }
  }
  __syncthreads();

  unsigned* op = partial + (size_t)blk * NBINS;
  for (int i = tid; i < NBINS; i += 256)
    op[i] = hist[0][i] + hist[1][i] + hist[2][i] + hist[3][i];
}

// ---------------- u64 shuffle helpers ----------------
__device__ inline unsigned long long shfl_up_u64(unsigned long long v, int off) {
  unsigned lo = (unsigned)v, hi = (unsigned)(v >> 32);
  lo = (unsigned)__shfl_up((int)lo, off, 64);
  hi = (unsigned)__shfl_up((int)hi, off, 64);
  return ((unsigned long long)hi << 32) | lo;
}
__device__ inline unsigned long long shfl_down_u64(unsigned long long v, int off) {
  unsigned lo = (unsigned)v, hi = (unsigned)(v >> 32);
  lo = (unsigned)__shfl_down((int)lo, off, 64);
  hi = (unsigned)__shfl_down((int)hi, off, 64);
  return ((unsigned long long)hi << 32) | lo;
}

// ---------------- Kernel C: merge partials + descending scan -> loss ----------------
__global__ __launch_bounds__(1024) void k_scan(
    const unsigned* __restrict__ partial,
    float* __restrict__ out) {
  int row  = blockIdx.x;                     // 0..167
  int tid  = threadIdx.x;
  int lane = tid & 63;
  int wave = tid >> 6;                       // 16 waves

  __shared__ unsigned long long hist0[NBINS];   // 16 KB
  __shared__ unsigned long long wtot[16];
  __shared__ double wred[16];
  __shared__ double sT;

  // merge 32 partials -> packed u64 (count<<32 | labelsum)
  #pragma unroll
  for (int bp = 0; bp < 2; ++bp) {
    int bn = bp * 1024 + tid;
    const unsigned* pp = partial + (size_t)row * NPARTS * NBINS + bn;
    unsigned long long s = 0;
    #pragma unroll
    for (int p = 0; p < NPARTS; ++p) {
      unsigned v = pp[(size_t)p * NBINS];
      s += ((unsigned long long)(v >> 18) << 32) | (unsigned long long)(v & 0x3FFFFu);
    }
    hist0[bn] = s;
  }
  __syncthreads();

  // total labelsum T (exact)
  unsigned long long tot = 0;
  for (int i = tid; i < NBINS; i += 1024) tot += hist0[i];
  #pragma unroll
  for (int off = 32; off > 0; off >>= 1) tot += shfl_down_u64(tot, off);
  if (lane == 0) wtot[wave] = tot;
  __syncthreads();
  if (tid == 0) {
    unsigned long long g = 0;
    #pragma unroll
    for (int w = 0; w < 16; ++w) g += wtot[w];
    sT = (double)(unsigned)(g & 0xffffffffULL);
  }
  __syncthreads();
  double T = sT;
  __syncthreads();

  // descending scan over 2048 bins: 2 chunks of 1024
  unsigned long long run = 0;
  double acc = 0.0;
  #pragma unroll
  for (int iter = 0; iter < 2; ++iter) {
    int d   = iter * 1024 + tid;
    int bin = (NBINS - 1) - d;
    unsigned long long v = hist0[bin];

    unsigned long long s = v;                 // intra-wave inclusive scan
    #pragma unroll
    for (int off = 1; off < 64; off <<= 1) {
      unsigned long long u = shfl_up_u64(s, off);
      if (lane >= off) s += u;
    }
    if (lane == 63) wtot[wave] = s;
    __syncthreads();

    unsigned long long woff = 0;
    for (int w = 0; w < wave; ++w) woff += wtot[w];
    unsigned long long excl = s - v + woff + run;  // strictly-greater prefix

    unsigned n = (unsigned)(v >> 32);
    if (n) {
      unsigned sl = (unsigned)(v & 0xffffffffu);
      unsigned cb = (unsigned)(excl >> 32);
      unsigned sb = (unsigned)(excl & 0xffffffffu);
      double Sb = (double)sb + (double)sl;
      double gb = 1.0 - (T - Sb) / (T + (double)(cb + n) - Sb);
      double ga = (cb == 0) ? 0.0
                            : 1.0 - (T - (double)sb) / (T + (double)cb - (double)sb);
      unsigned key = (unsigned)bin;
      unsigned ex5 = key >> 7, mant = key & 127u;
      float e = (ex5 == 0) ? 0.0f
              : ldexpf(1.0f + ((float)mant + 0.5f) * 0.0078125f, (int)ex5 - 15);
      acc += (double)e * (gb - ga);
    }

    unsigned long long ct = 0;
    #pragma unroll
    for (int w = 0; w < 16; ++w) ct += wtot[w];
    run += ct;
    __syncthreads();
  }

  // block reduce acc
  #pragma unroll
  for (int off = 32; off > 0; off >>= 1) acc += __shfl_down(acc, off, 64);
  if (lane == 0) wred[wave] = acc;
  __syncthreads();
  if (tid == 0) {
    double ssum = 0.0;
    #pragma unroll
    for (int w = 0; w < 16; ++w) ssum += wred[w];
    atomicAdd(out, (float)(ssum * (1.0 / (double)NROWS)));
  }
}

extern "C" void kernel_launch(void* const* d_in, const int* in_sizes, int n_in,
                              void* d_out, int out_size, void* d_ws, size_t ws_size,
                              hipStream_t stream) {
  const float* x  = (const float*)d_in[0];   // (B, C, H, W) float32
  const int* tgt  = (const int*)d_in[1];     // (B, H, W) int
  float* out      = (float*)d_out;

  unsigned short* pk = (unsigned short*)d_ws;                 // 88 MB keys
  unsigned* partial  = (unsigned*)((char*)d_ws + (size_t)NROWS * NPIX * 2); // 44 MB

  hipMemsetAsync(d_out, 0, sizeof(float), stream);

  int quads = NB * NPIX / 4;                 // 524288
  k_err<<<quads / 256, 256, 0, stream>>>(x, tgt, pk);
  k_hist<<<NROWS * NPARTS, 256, 0, stream>>>(pk, partial);
  k_scan<<<NROWS, 1024, 0, stream>>>(partial, out);
}

// Round 4
// 270.609 us; speedup vs baseline: 1.1330x; 1.1330x over previous
//
#include <hip/hip_runtime.h>

// LovaszSoftmaxLoss B=8, C=21, H=W=512 — sort-free counting-sort formulation.
// loss = sum_i e_i*(g_i - g_{i-1}) over descending-sorted errors; equal-key
// runs contribute e*(g(b)-g(a-1)) independent of tie order, so a histogram
// over quantized keys suffices. Key = 12 octaves x 6 mantissa bits = 768 bins
// (bin-center rel error 0.78% vs 2% threshold; e<2^-12 -> bin 0, contribution
// <= ~1e-4 relative).
//
// R3 post-mortem: restructuring atomics (u64->u32, 32x more blocks) changed
// nothing -> atomics are NOT the bottleneck; multi-pass HBM traffic is.
// R4: fully fused softmax->error->histogram (21 class-histograms x 768 bins
// x u32 packed (count<<18|labelsum) = 63KB LDS per block), writes only 33MB
// of partials. Total traffic 184+33+33 MB vs R3's ~450 MB.

#define NB    8
#define NC    21
#define NPIX  262144
#define NROWS (NB * NC)      // 168
#define NBINS 768            // key = (fexp+12)<<6 | mant6 ; fexp in [-12,0]
#define BPB   64             // blocks per batch
#define CHUNK (NPIX / BPB)   // 4096 pixels per block

// ---------------- Fused kernel: softmax -> error -> per-block LDS histograms ----------------
// 512 threads, 8 pixels/thread (2 float4 groups). count<=4096 (14b), labelsum<=81920 (18b).
__global__ __launch_bounds__(512, 4) void k_fused(
    const float* __restrict__ x,
    const int* __restrict__ tgt,
    unsigned* __restrict__ partial) {
  __shared__ unsigned hist[NC * NBINS];      // 63 KB
  int tid = threadIdx.x;
  for (int i = tid; i < NC * NBINS; i += 512) hist[i] = 0;
  __syncthreads();

  int b     = blockIdx.x >> 6;
  int chunk = blockIdx.x & 63;
  const float* xb = x + (size_t)b * NC * NPIX + (size_t)chunk * CHUNK;
  const int*   tb = tgt + (size_t)b * NPIX + (size_t)chunk * CHUNK;

  #pragma unroll
  for (int g = 0; g < 2; ++g) {
    int n4 = (g * 512 + tid) * 4;            // 0..4092, coalesced float4

    float v[NC][4];
    float m[4] = {-3.4e38f, -3.4e38f, -3.4e38f, -3.4e38f};
    #pragma unroll
    for (int c = 0; c < NC; ++c) {
      float4 t = *(const float4*)(xb + (size_t)c * NPIX + n4);
      v[c][0] = t.x; v[c][1] = t.y; v[c][2] = t.z; v[c][3] = t.w;
      m[0] = fmaxf(m[0], t.x); m[1] = fmaxf(m[1], t.y);
      m[2] = fmaxf(m[2], t.z); m[3] = fmaxf(m[3], t.w);
    }
    float Z[4] = {0.f, 0.f, 0.f, 0.f};
    #pragma unroll
    for (int c = 0; c < NC; ++c) {
      #pragma unroll
      for (int j = 0; j < 4; ++j) {
        v[c][j] = __expf(v[c][j] - m[j]);
        Z[j] += v[c][j];
      }
    }
    float iZ[4];
    #pragma unroll
    for (int j = 0; j < 4; ++j) iZ[j] = 1.0f / Z[j];

    int4 tv = *(const int4*)(tb + n4);
    int tl[4] = {tv.x, tv.y, tv.z, tv.w};

    #pragma unroll
    for (int c = 0; c < NC; ++c) {
      unsigned* hr = hist + c * NBINS;
      #pragma unroll
      for (int j = 0; j < 4; ++j) {
        float p = v[c][j] * iZ[j];
        float e = fabsf(((c == tl[j]) ? 1.0f : 0.0f) - p);   // e in [0,1]
        unsigned fb   = __float_as_uint(e);
        int      fexp = (int)(fb >> 23) - 127;
        unsigned key;
        if (fexp < -12) key = 0u;
        else {
          key = (((unsigned)(fexp + 12)) << 6) | ((fb >> 17) & 63u);
          if (key > NBINS - 1) key = NBINS - 1;              // e==1.0 / safety
        }
        atomicAdd(hr + key, (1u << 18) | (unsigned)tl[j]);
      }
    }
  }
  __syncthreads();

  unsigned* op = partial + (size_t)blockIdx.x * NC * NBINS;
  for (int i = tid; i < NC * NBINS; i += 512) op[i] = hist[i];
}

// ---------------- u64 shuffle helpers ----------------
__device__ inline unsigned long long shfl_up_u64(unsigned long long v, int off) {
  unsigned lo = (unsigned)v, hi = (unsigned)(v >> 32);
  lo = (unsigned)__shfl_up((int)lo, off, 64);
  hi = (unsigned)__shfl_up((int)hi, off, 64);
  return ((unsigned long long)hi << 32) | lo;
}
__device__ inline unsigned long long shfl_down_u64(unsigned long long v, int off) {
  unsigned lo = (unsigned)v, hi = (unsigned)(v >> 32);
  lo = (unsigned)__shfl_down((int)lo, off, 64);
  hi = (unsigned)__shfl_down((int)hi, off, 64);
  return ((unsigned long long)hi << 32) | lo;
}

// ---------------- Scan kernel: merge 64 partials/row + descending scan ----------------
// 168 blocks x 768 threads (12 waves); one thread per bin.
__global__ __launch_bounds__(768) void k_scan(
    const unsigned* __restrict__ partial,
    float* __restrict__ out) {
  int row  = blockIdx.x;                     // 0..167
  int b    = row / NC;
  int c    = row - b * NC;
  int tid  = threadIdx.x;                    // == bin slot
  int lane = tid & 63;
  int wave = tid >> 6;                       // 12 waves

  __shared__ unsigned long long hist0[NBINS];   // 6 KB
  __shared__ unsigned long long wtot[12];
  __shared__ double wred[12];
  __shared__ double sT;

  // merge 64 block-partials for (b, c): coalesced 768-wide loads
  {
    const unsigned* pp = partial + ((size_t)(b * BPB) * NC + c) * NBINS + tid;
    unsigned long long cnt = 0, ls = 0;
    #pragma unroll 8
    for (int j = 0; j < BPB; ++j) {
      unsigned v = pp[(size_t)j * NC * NBINS];
      cnt += (v >> 18);
      ls  += (v & 0x3FFFFu);
    }
    hist0[tid] = (cnt << 32) | ls;
  }
  __syncthreads();

  // total labelsum T (exact; fields can't overflow: cnt<=262144, ls<=5.3M)
  unsigned long long tot = hist0[tid];
  #pragma unroll
  for (int off = 32; off > 0; off >>= 1) tot += shfl_down_u64(tot, off);
  if (lane == 0) wtot[wave] = tot;
  __syncthreads();
  if (tid == 0) {
    unsigned long long g = 0;
    #pragma unroll
    for (int w = 0; w < 12; ++w) g += wtot[w];
    sT = (double)(unsigned)(g & 0xffffffffULL);
  }
  __syncthreads();
  double T = sT;
  __syncthreads();

  // single-chunk descending scan over 768 bins
  int bin = (NBINS - 1) - tid;
  unsigned long long v = hist0[bin];

  unsigned long long s = v;                  // intra-wave inclusive scan
  #pragma unroll
  for (int off = 1; off < 64; off <<= 1) {
    unsigned long long u = shfl_up_u64(s, off);
    if (lane >= off) s += u;
  }
  if (lane == 63) wtot[wave] = s;
  __syncthreads();

  unsigned long long woff = 0;
  for (int w = 0; w < wave; ++w) woff += wtot[w];
  unsigned long long excl = s - v + woff;    // strictly-greater prefix

  double acc = 0.0;
  unsigned n = (unsigned)(v >> 32);
  if (n) {
    unsigned sl = (unsigned)(v & 0xffffffffu);
    unsigned cb = (unsigned)(excl >> 32);
    unsigned sb = (unsigned)(excl & 0xffffffffu);
    double Sb = (double)sb + (double)sl;
    double gb = 1.0 - (T - Sb) / (T + (double)(cb + n) - Sb);
    double ga = (cb == 0) ? 0.0
                          : 1.0 - (T - (double)sb) / (T + (double)cb - (double)sb);
    unsigned key = (unsigned)bin;
    unsigned ex  = key >> 6, mant = key & 63u;
    float e = ldexpf(1.0f + ((float)mant + 0.5f) * 0.015625f, (int)ex - 12);
    acc = (double)e * (gb - ga);
  }

  // block reduce acc (12 waves)
  #pragma unroll
  for (int off = 32; off > 0; off >>= 1) acc += __shfl_down(acc, off, 64);
  if (lane == 0) wred[wave] = acc;
  __syncthreads();
  if (tid == 0) {
    double ssum = 0.0;
    #pragma unroll
    for (int w = 0; w < 12; ++w) ssum += wred[w];
    atomicAdd(out, (float)(ssum * (1.0 / (double)NROWS)));
  }
}

extern "C" void kernel_launch(void* const* d_in, const int* in_sizes, int n_in,
                              void* d_out, int out_size, void* d_ws, size_t ws_size,
                              hipStream_t stream) {
  const float* x  = (const float*)d_in[0];   // (B, C, H, W) float32
  const int* tgt  = (const int*)d_in[1];     // (B, H, W) int32
  float* out      = (float*)d_out;
  unsigned* partial = (unsigned*)d_ws;       // 512*21*768*4 = 33 MB

  hipMemsetAsync(d_out, 0, sizeof(float), stream);
  k_fused<<<NB * BPB, 512, 0, stream>>>(x, tgt, partial);
  k_scan<<<NROWS, NBINS, 0, stream>>>(partial, out);
}